// Round 19
// baseline (73.333 us; speedup 1.0000x reference)
//
#include <hip/hip_runtime.h>
#include <hip/hip_bf16.h>
#include <math.h>

#define G 4
#define T 2048
#define H 1024
#define E 8
#define NBUK 2048  // 11-bit radix buckets (key>>53)
#define K1B 2048   // K1 blocks (4 token-waves each)
#define K2B 256    // K2 blocks = 32 (g,e) x 8 slices

typedef float f4 __attribute__((ext_vector_type(4)));
typedef unsigned long long u64;

// ---------------------------------------------------------------------------
// R19 = R18 (best, 73.2us) with ONE change: K2's combine writes INTERLEAVED
// STRIPES (8 blocks/ge x 15KB stripes @ 120KB stride) instead of contiguous
// 384KB per-block slabs. Deconfounded slab-vs-stripe A/B: fast streams (K1
// zero, harness memset ~6-7TB/s) are interleaved; slow ones (~3TB/s) are
// slabs. Stride & stripe both multiples of mc4 -> thread column invariant ->
// register-hoisted load-free body preserved. All numerics byte-identical.
//
// K1 (R13/R18 verbatim): zero-stripe dispatch half + logits->u64 keys.
// fp64 path FROZEN (absmax=0.0 R2-R18). key = prob_bits<<32 | ~t.
// ---------------------------------------------------------------------------
__global__ __launch_bounds__(256) void k1_zero_logits(
    const float* __restrict__ x, const float* __restrict__ W,
    const float* __restrict__ b, u64* __restrict__ keys,
    float* __restrict__ lse2, float* __restrict__ out, unsigned n4d) {
  unsigned bid = blockIdx.x;
  unsigned tid = threadIdx.x;

  {
    f4* outD = (f4*)out;
    f4 z = {0.0f, 0.0f, 0.0f, 0.0f};
    for (unsigned i = bid * 256u + tid; i < n4d; i += K1B * 256u) outD[i] = z;
  }

  int wave = (int)(bid * 4 + (tid >> 6));
  int lane = (int)(tid & 63);
  const float* xr = x + (size_t)wave * H;

  double acc0 = 0, acc1 = 0, acc2 = 0, acc3 = 0;
  double acc4 = 0, acc5 = 0, acc6 = 0, acc7 = 0;
#pragma unroll
  for (int j = 0; j < 4; ++j) {
    int hbase = j * 256 + lane * 4;
    f4 xv = *(const f4*)(xr + hbase);
#pragma unroll
    for (int k = 0; k < 4; ++k) {
      const float* wr = W + (size_t)(hbase + k) * 8;
      f4 w0 = *(const f4*)(wr);
      f4 w1 = *(const f4*)(wr + 4);
      double xd = (double)xv[k];
      acc0 += xd * (double)w0[0];
      acc1 += xd * (double)w0[1];
      acc2 += xd * (double)w0[2];
      acc3 += xd * (double)w0[3];
      acc4 += xd * (double)w1[0];
      acc5 += xd * (double)w1[1];
      acc6 += xd * (double)w1[2];
      acc7 += xd * (double)w1[3];
    }
  }
#pragma unroll
  for (int off = 32; off >= 1; off >>= 1) {
    acc0 += __shfl_xor(acc0, off);
    acc1 += __shfl_xor(acc1, off);
    acc2 += __shfl_xor(acc2, off);
    acc3 += __shfl_xor(acc3, off);
    acc4 += __shfl_xor(acc4, off);
    acc5 += __shfl_xor(acc5, off);
    acc6 += __shfl_xor(acc6, off);
    acc7 += __shfl_xor(acc7, off);
  }
  double l0 = acc0 + (double)b[0], l1 = acc1 + (double)b[1];
  double l2 = acc2 + (double)b[2], l3 = acc3 + (double)b[3];
  double l4 = acc4 + (double)b[4], l5 = acc5 + (double)b[5];
  double l6 = acc6 + (double)b[6], l7 = acc7 + (double)b[7];
  double m = fmax(fmax(fmax(l0, l1), fmax(l2, l3)),
                  fmax(fmax(l4, l5), fmax(l6, l7)));
  double la = (lane & 1) ? l1 : l0;
  double lb = (lane & 1) ? l3 : l2;
  double lc = (lane & 1) ? l5 : l4;
  double ld = (lane & 1) ? l7 : l6;
  double le = (lane & 2) ? lb : la;
  double lf = (lane & 2) ? ld : lc;
  double lsel = (lane & 4) ? lf : le;

  double pe = exp(lsel - m);
  double s = pe;
  s += __shfl_xor(s, 1);
  s += __shfl_xor(s, 2);
  s += __shfl_xor(s, 4);  // bitwise == reference's add tree
  double inv = 1.0 / s;
  float pf = (float)(pe * inv);

  int g = wave >> 11;
  int t = wave & (T - 1);
  if (lane < 8) {
    keys[((size_t)g * 8 + lane) * T + t] =
        ((u64)__float_as_uint(pf) << 32) | (unsigned)(~t);
  }
  if (lane == 0) {
    double lse = m + log(s);
    lse2[wave] = (float)(lse * lse);
  }
}

// ---------------------------------------------------------------------------
// K2: 256 blocks = 32 (g,e) x 8 slices. Redundant radix select per (g,e)
// (bit-exact R9-R18), gate in LDS; ones written by slice 0 only; combine
// written as load-free register-sourced INTERLEAVED stripes (this round's
// single change). Block 0 appends z-loss.
// ---------------------------------------------------------------------------
__global__ __launch_bounds__(1024) void k2_select_combine(
    const u64* __restrict__ keys, const float* __restrict__ lse2,
    float* __restrict__ out, unsigned n4d, int max_cap, int ec) {
  __shared__ int hist[NBUK];
  __shared__ int sA[NBUK];
  __shared__ int sB[NBUK];
  __shared__ int cur[NBUK];
  __shared__ u64 srt[T];
  __shared__ float gLds[1024];
  __shared__ double red[256];

  unsigned bid = blockIdx.x;
  unsigned tid = threadIdx.x;
  unsigned mc = (unsigned)max_cap;
  unsigned mc4 = mc >> 2;
  int ge = (int)(bid >> 3);
  int sl = (int)(bid & 7);

  hist[tid] = 0;
  hist[tid + 1024] = 0;
  if (tid < mc) gLds[tid] = 0.0f;
  __syncthreads();

  const u64* kcol = keys + (size_t)ge * T;
  u64 k0 = kcol[tid];
  u64 k1 = kcol[tid + 1024];
  int b0 = (int)(k0 >> 53);
  int b1 = (int)(k1 >> 53);
  atomicAdd(&hist[b0], 1);
  atomicAdd(&hist[b1], 1);
  __syncthreads();

  sA[tid] = hist[tid];
  sA[tid + 1024] = hist[tid + 1024];
  __syncthreads();
  int* src = sA;
  int* dst = sB;
  for (int s = 1; s < NBUK; s <<= 1) {
    for (int i = (int)tid; i < NBUK; i += 1024) {
      int v = src[i];
      if (i + s < NBUK) v += src[i + s];
      dst[i] = v;
    }
    __syncthreads();
    int* tmp = src;
    src = dst;
    dst = tmp;
  }
  for (int i = (int)tid; i < NBUK; i += 1024) cur[i] = src[i] - hist[i];
  __syncthreads();

  int p0 = atomicAdd(&cur[b0], 1);
  srt[p0] = k0;
  int p1 = atomicAdd(&cur[b1], 1);
  srt[p1] = k1;
  __syncthreads();

  const double factors[8] = {0.5, 0.75, 1.0, 1.0, 1.25, 1.25, 1.5, 1.5};
  int cap = (int)((double)ec * factors[ge & 7]);

  int o0 = src[b0] - hist[b0];
  if (o0 < cap) {
    int end = src[b0];
    int c = 0;
    for (int i = o0; i < end; ++i) c += (int)(srt[i] > k0);
    int r = o0 + c;
    if (r < cap) {
      unsigned t = ~(unsigned)k0;
      gLds[r] = __uint_as_float((unsigned)(k0 >> 32));
      if (sl == 0) out[((size_t)ge * T + t) * mc + r] = 1.0f;
    }
  }
  int o1 = src[b1] - hist[b1];
  if (o1 < cap) {
    int end = src[b1];
    int c = 0;
    for (int i = o1; i < end; ++i) c += (int)(srt[i] > k1);
    int r = o1 + c;
    if (r < cap) {
      unsigned t = ~(unsigned)k1;
      gLds[r] = __uint_as_float((unsigned)(k1 >> 32));
      if (sl == 0) out[((size_t)ge * T + t) * mc + r] = 1.0f;
    }
  }
  __syncthreads();  // gLds complete

  // combine: 8 blocks of this ge write INTERLEAVED 960-f4 stripes at 7680-f4
  // stride across the ge's full T*mc4 region. 960%96==0 and 7680%96==0 ->
  // column (off%mc4) == tid%mc4 is thread-invariant -> load-free body.
  {
    unsigned gslab = (unsigned)T * mc4;   // 196608 for mc=384
    unsigned rowspan = 1024u / mc4;       // 10
    unsigned active = rowspan * mc4;      // 960
    unsigned stride = 8u * active;        // 7680
    f4* dstC = (f4*)out + n4d + (size_t)ge * gslab;
    if (tid < active) {
      f4 gv = ((const f4*)gLds)[tid % mc4];  // one LDS read, then store-only
      for (unsigned off = (unsigned)sl * active + tid; off < gslab;
           off += stride)
        dstC[off] = gv;
    }
  }

  // z-loss (block 0; proven 256-thread shape, bit-identical)
  if (bid == 0) {
    if (tid < 256) {
      double s = 0.0;
      for (int i = (int)tid; i < G * T; i += 256) s += (double)lse2[i];
      red[tid] = s;
    }
    __syncthreads();
    for (int off = 128; off > 0; off >>= 1) {
      if ((int)tid < off) red[tid] += red[tid + off];
      __syncthreads();
    }
    if (tid == 0) {
      size_t ne = (size_t)n4d * 4;
      out[2 * ne] = 0.0f;                                   // auxiliary_loss
      out[2 * ne + 1] = (float)(red[0] / (double)(G * T));  // z_loss
    }
  }
}

extern "C" void kernel_launch(void* const* d_in, const int* in_sizes, int n_in,
                              void* d_out, int out_size, void* d_ws,
                              size_t ws_size, hipStream_t stream) {
  const float* x = (const float*)d_in[0];
  const float* W = (const float*)d_in[1];
  const float* b = (const float*)d_in[2];

  // Derive max_cap from out_size: out = 2*G*E*T*max_cap + 2 scalars.
  long long body = (long long)out_size - 2;
  int max_cap = (int)(body / (2LL * G * E * T));  // 384 for ec=256
  if (max_cap <= 0) return;
  int ec = (2 * max_cap) / 3;  // max factor is 1.5

  u64* keys = (u64*)d_ws;                            // 32*2048 u64 = 512 KB
  float* lse2 = (float*)(keys + (size_t)G * E * T);  // 8192 floats

  unsigned n4d = (unsigned)((long long)G * E * T * max_cap / 4);  // per array

  k1_zero_logits<<<K1B, 256, 0, stream>>>(x, W, b, keys, lse2, (float*)d_out,
                                          n4d);
  k2_select_combine<<<K2B, 1024, 0, stream>>>(keys, lse2, (float*)d_out, n4d,
                                              max_cap, ec);
}